// Round 1
// 10694.048 us; speedup vs baseline: 1.2364x; 1.2364x over previous
//
#include <hip/hip_runtime.h>
#include <stdint.h>

// LSTM final-h. B=128, T=1024, I=256, H=512. Inputs fp32, output fp32.
// R8: coherence rework. R7 (13.2ms, 12.9us/step) ran 2x __threadfence()
// per block-step -> buffer_inv+buffer_wbl2 storms (256 invs/step device-
// wide) that evicted x and h from L2 every step and serialized on the
// XCD L2. MfmaUtil was 2.9% => ~92% of each step was sync machinery.
// Now:
//  - h-part reads: inline-asm global_load_dwordx4 sc0 sc1 (read the LLC
//    directly, bypass L1/L2) -> NO acquire fence, no buffer_inv anywhere.
//    x and the LDS-resident weights stay cached in L2 across all steps.
//  - producer: plain h stores -> __syncthreads (per-wave vmcnt drain) ->
//    tid0 RELEASE atomic flag store (waitcnt + buffer_wbl2 + store; the
//    wbl2 pushes the h lines to LLC; no invalidate emitted).
//  - h loads software-pipelined: all 32x16B issued, counted
//    s_waitcnt vmcnt(24/16/8/0) per 4-ks chunk; sched_barrier(0x104)
//    after each wait so MFMAs cannot hoist past the inline-asm waitcnt
//    (compiler does this otherwise - reg-only MFMA ignores "memory").
//    Safe vs foreign VMEM ops: the chunk region is bounded by barriers
//    on both sides, so only our volatile-asm loads are in flight.
//  - accumulator split (a0m/a0c): dependent-MFMA chain 48 -> 32 deep.
// Numerics: identical math, fp32 accumulate, only summation grouping
// changed (main vs compensation accumulated separately, added at end).

#define Bsz 128
#define Tsz 1024
#define Isz 256
#define Hsz 512
#define NBLK 128
#define NTHREADS 256

typedef __attribute__((ext_vector_type(8))) short short8;
typedef __attribute__((ext_vector_type(4))) float float4v;

__device__ __forceinline__ float b2f(unsigned short u) {
  union { float f; unsigned int i; } v; v.i = ((unsigned int)u) << 16; return v.f;
}
__device__ __forceinline__ unsigned short f2b(float f) {
  unsigned int u = __float_as_uint(f);
  return (unsigned short)((u + 0x7fffu + ((u >> 16) & 1u)) >> 16);
}
__device__ __forceinline__ float sigmf(float x) { return 1.0f / (1.0f + __expf(-x)); }
__device__ __forceinline__ float tanhf_fast(float x) {
  float e = __expf(-2.0f * fabsf(x));
  float t = (1.0f - e) / (1.0f + e);
  return copysignf(t, x);
}
__device__ __forceinline__ short8 cvt8(const float* p) {
  float4 u = *(const float4*)(p);
  float4 v = *(const float4*)(p + 4);
  short8 r;
  r[0] = (short)f2b(u.x); r[1] = (short)f2b(u.y);
  r[2] = (short)f2b(u.z); r[3] = (short)f2b(u.w);
  r[4] = (short)f2b(v.x); r[5] = (short)f2b(v.y);
  r[6] = (short)f2b(v.z); r[7] = (short)f2b(v.w);
  return r;
}

#define MFMA(A, B, C) __builtin_amdgcn_mfma_f32_16x16x32_bf16((A), (B), (C), 0, 0, 0)

// LLC-direct 16B load: bypasses L1 and the (possibly stale) per-XCD L2.
// Must stay volatile: ordering vs the counted s_waitcnt asm below relies
// on volatile-asm program order.
#define LLD(dst, base, OFFB)                                              \
  asm volatile("global_load_dwordx4 %0, %1, off offset:" OFFB " sc0 sc1"  \
               : "=v"(dst) : "v"(base))

// Issue one 4-ks chunk: 4x hi + 4x lo (8 loads, 128B/lane).
#define LCHUNK(c, O0, O1, O2, O3)                                         \
  LLD(hb[4 * (c) + 0], hh, O0); LLD(hb[4 * (c) + 1], hh, O1);             \
  LLD(hb[4 * (c) + 2], hh, O2); LLD(hb[4 * (c) + 3], hh, O3);             \
  LLD(lb[4 * (c) + 0], hl, O0); LLD(lb[4 * (c) + 1], hl, O1);             \
  LLD(lb[4 * (c) + 2], hl, O2); LLD(lb[4 * (c) + 3], hl, O3)

// One K-slice of the h-part. Main terms into a0m/a1m, compensation terms
// into a0c/a1c (halves the dependent chain vs single accumulator).
#define HSTEP(ks) do {                                                    \
    short8 bh0 = whi[(8 + (ks)) * 64 + lane];                             \
    short8 bh1 = whi[1536 + (8 + (ks)) * 64 + lane];                      \
    short8 bl0 = wlo[(ks) * 64 + lane];                                   \
    short8 bl1 = wlo[1024 + (ks) * 64 + lane];                            \
    a0m = MFMA(hb[(ks)], bh0, a0m);                                       \
    a1m = MFMA(hb[(ks)], bh1, a1m);                                       \
    a0c = MFMA(hb[(ks)], bl0, a0c);                                       \
    a1c = MFMA(hb[(ks)], bl1, a1c);                                       \
    a0c = MFMA(lb[(ks)], bh0, a0c);                                       \
    a1c = MFMA(lb[(ks)], bh1, a1c);                                       \
  } while (0)

__global__ __launch_bounds__(NTHREADS, 1) void lstm_persistent(
    const float* __restrict__ x,
    const float* __restrict__ wih,
    const float* __restrict__ whh,
    const float* __restrict__ bih,
    const float* __restrict__ bhh,
    float* __restrict__ out,
    unsigned short* __restrict__ hhi0,
    unsigned short* __restrict__ hhi1,
    unsigned short* __restrict__ hlo0,
    unsigned short* __restrict__ hlo1,
    unsigned int* __restrict__ flags)   // 2 domains x 64 flags x 32 dwords
{
  __shared__ short8 whi[2 * 24 * 64];  // 48 KB: W_ih|W_hh hi
  __shared__ short8 wlo[2 * 16 * 64];  // 32 KB: W_hh lo

  const int tid  = threadIdx.x;
  const int blk  = blockIdx.x;
  const int hb_g = blk & 63;   // hidden group: units j0..j0+7; also idx in domain
  const int bb   = blk >> 6;   // batch half == sync domain
  const int j0   = hb_g * 8;
  const int rb   = bb * 64;
  const int w    = tid >> 6;
  const int lane = tid & 63;
  const int l15  = lane & 15;
  const int kq   = lane >> 4;

  unsigned int* dfl = flags + (size_t)bb * 64 * 32;  // this domain's flags
  unsigned int* myf = dfl + (size_t)hb_g * 32;       // this block's flag

  // ---- prepack W into LDS as bf16 MFMA B-fragments (hi + lo for W_hh) ----
  for (int idx = tid; idx < 3072; idx += NTHREADS) {
    int nt  = (idx >= 1536) ? 1 : 0;
    int rem = idx - nt * 1536;
    int ks  = rem >> 6;
    int ln  = rem & 63;
    int col = nt * 16 + (ln & 15);
    int k   = ks * 32 + (ln >> 4) * 8;
    int grow = (col >> 3) * Hsz + j0 + (col & 7);
    const float* src = (ks < 8) ? (wih + (size_t)grow * Isz + k)
                                : (whh + (size_t)grow * Hsz + (k - Isz));
    float wv[8];
#pragma unroll
    for (int j = 0; j < 8; ++j) wv[j] = src[j];
    short8 hi;
#pragma unroll
    for (int j = 0; j < 8; ++j) hi[j] = (short)f2b(wv[j]);
    whi[idx] = hi;
    if (ks >= 8) {
      short8 lo;
#pragma unroll
      for (int j = 0; j < 8; ++j)
        lo[j] = (short)f2b(wv[j] - b2f((unsigned short)hi[j]));
      wlo[nt * 1024 + (ks - 8) * 64 + ln] = lo;
    }
  }

  const int colA = l15;
  const int colB = 16 + l15;
  const int gA = (colA >> 3) * Hsz + j0 + (colA & 7);
  const int gB = (colB >> 3) * Hsz + j0 + (colB & 7);
  const float biasA = bih[gA] + bhh[gA];
  const float biasB = bih[gB] + bhh[gB];

  __syncthreads();

  const int arow = rb + w * 16 + l15;
  const float* xrow = x + (size_t)arow * (Tsz * Isz) + kq * 8;

  float cst[4] = {0.f, 0.f, 0.f, 0.f};
  const int rbase0 = rb + w * 16 + kq * 4;
  const int gcol   = j0 + (l15 & 7);

  for (int t = 0; t < Tsz; ++t) {
    float4v a0m = {0.f, 0.f, 0.f, 0.f};
    float4v a1m = {0.f, 0.f, 0.f, 0.f};
    float4v a0c = {0.f, 0.f, 0.f, 0.f};
    float4v a1c = {0.f, 0.f, 0.f, 0.f};
    const float* xp = xrow + (size_t)t * Isz;

    // ---- x-part first: independent of other blocks (hides barrier skew).
    // Normal cached loads: with no buffer_inv anywhere these now hit L2. ----
#pragma unroll
    for (int ks = 0; ks < 8; ++ks) {
      short8 av = cvt8(xp + ks * 32);
      short8 b0 = whi[ks * 64 + lane];
      short8 b1 = whi[1536 + ks * 64 + lane];
      a0m = MFMA(av, b0, a0m);
      a1m = MFMA(av, b1, a1m);
    }

    // ---- wait for step-t h from all blocks in this domain (relaxed poll,
    // NO acquire fence: the h loads below bypass L1/L2 by construction) ----
    if (t > 0) {
      if (tid < 64) {
        const unsigned int* f = dfl + (size_t)tid * 32;
        int guard = 0;
        while (__hip_atomic_load(f, __ATOMIC_RELAXED, __HIP_MEMORY_SCOPE_AGENT)
               < (unsigned)t) {
          __builtin_amdgcn_s_sleep(1);
          if (++guard > (1 << 26)) break;  // fail loud, not hang
        }
      }
      __syncthreads();
    }

    const unsigned short* hh = ((t & 1) ? hhi1 : hhi0) + (size_t)arow * Hsz + kq * 8;
    const unsigned short* hl = ((t & 1) ? hlo1 : hlo0) + (size_t)arow * Hsz + kq * 8;

    // ---- issue all 32 LLC loads (512B/lane), then consume in 4 chunks
    // with counted waits. In-order vmcnt retirement makes the counts
    // exact; barriers on both sides keep foreign VMEM out of the window. ----
    short8 hb[16], lb[16];
    LCHUNK(0, "0",   "64",  "128", "192");
    LCHUNK(1, "256", "320", "384", "448");
    LCHUNK(2, "512", "576", "640", "704");
    LCHUNK(3, "768", "832", "896", "960");

    asm volatile("s_waitcnt vmcnt(24)");
    __builtin_amdgcn_sched_barrier(0x104);  // allow DS_READ+SALU across, pin MFMA
    HSTEP(0); HSTEP(1); HSTEP(2); HSTEP(3);
    asm volatile("s_waitcnt vmcnt(16)");
    __builtin_amdgcn_sched_barrier(0x104);
    HSTEP(4); HSTEP(5); HSTEP(6); HSTEP(7);
    asm volatile("s_waitcnt vmcnt(8)");
    __builtin_amdgcn_sched_barrier(0x104);
    HSTEP(8); HSTEP(9); HSTEP(10); HSTEP(11);
    asm volatile("s_waitcnt vmcnt(0)");
    __builtin_amdgcn_sched_barrier(0x104);
    HSTEP(12); HSTEP(13); HSTEP(14); HSTEP(15);

    // bias + gate exchange (i<->f, g<->o live in lanes l and l^8)
    float v0[4], v1[4], p0[4], p1[4];
#pragma unroll
    for (int r = 0; r < 4; ++r) {
      v0[r] = a0m[r] + a0c[r] + biasA;
      v1[r] = a1m[r] + a1c[r] + biasB;
      p0[r] = __shfl_xor(v0[r], 8, 64);
      p1[r] = __shfl_xor(v1[r], 8, 64);
    }
    if (l15 < 8) {
      unsigned short* dhh = (t & 1) ? hhi0 : hhi1;
      unsigned short* dhl = (t & 1) ? hlo0 : hlo1;
#pragma unroll
      for (int r = 0; r < 4; ++r) {
        float ig = sigmf(v0[r]);
        float fg = sigmf(p0[r]);
        float gg = tanhf_fast(v1[r]);
        float og = sigmf(p1[r]);
        float c  = fg * cst[r] + ig * gg;
        cst[r] = c;
        float hv = og * tanhf_fast(c);
        int off = (rbase0 + r) * Hsz + gcol;
        if (t == Tsz - 1) {
          out[off] = hv;                    // fp32 output
        } else {
          unsigned short hb16 = f2b(hv);
          dhh[off] = hb16;
          dhl[off] = f2b(hv - b2f(hb16));
        }
      }
    }

    if (t != Tsz - 1) {
      __syncthreads();  // all waves' h stores acked (per-wave vmcnt drain)
      if (tid == 0) {
        // RELEASE store: s_waitcnt vmcnt(0) + buffer_wbl2 + flag store.
        // Pushes this block's dirty h lines to LLC; emits NO invalidate,
        // so x / L2 locality survive across steps.
        __hip_atomic_store(myf, (unsigned)(t + 1),
                           __ATOMIC_RELEASE, __HIP_MEMORY_SCOPE_AGENT);
      }
      // no trailing syncthreads: next iteration's poll has its own barrier
    }
  }
}

extern "C" void kernel_launch(void* const* d_in, const int* in_sizes, int n_in,
                              void* d_out, int out_size, void* d_ws, size_t ws_size,
                              hipStream_t stream) {
  if (n_in < 5) return;
  long long s0 = in_sizes[0], s1 = in_sizes[1], s2 = in_sizes[2],
            s3 = in_sizes[3], s4 = in_sizes[4];
  if (!(s1 > 0 && s3 > 0 && s0 == 64 * s1 && s2 == 2 * s1 &&
        s1 == 256 * s3 && s3 == s4)) return;

  const float* x   = (const float*)d_in[0];
  const float* wih = (const float*)d_in[1];
  const float* whh = (const float*)d_in[2];
  const float* bih = (const float*)d_in[3];
  const float* bhh = (const float*)d_in[4];
  float* out = (float*)d_out;

  char* ws = (char*)d_ws;
  const size_t FLAGS_BYTES = 2 * 64 * 32 * 4;  // 16 KB
  const size_t HB = (size_t)Bsz * Hsz * 2;     // 128 KB per bf16 h buffer
  unsigned int*   flags = (unsigned int*)ws;
  unsigned short* hhi0 = (unsigned short*)(ws + FLAGS_BYTES);
  unsigned short* hhi1 = (unsigned short*)(ws + FLAGS_BYTES + HB);
  unsigned short* hlo0 = (unsigned short*)(ws + FLAGS_BYTES + 2 * HB);
  unsigned short* hlo1 = (unsigned short*)(ws + FLAGS_BYTES + 3 * HB);

  hipMemsetAsync(d_ws, 0, FLAGS_BYTES + 4 * HB, stream);

  hipLaunchKernelGGL(lstm_persistent, dim3(NBLK), dim3(NTHREADS), 0, stream,
                     x, wih, whh, bih, bhh, out, hhi0, hhi1, hlo0, hlo1, flags);
}

// Round 2
// 8451.390 us; speedup vs baseline: 1.5644x; 1.2654x over previous
//
#include <hip/hip_runtime.h>
#include <stdint.h>

// LSTM final-h. B=128, T=1024, I=256, H=512. Inputs fp32, output fp32.
// R9: kill buffer_wbl2. R8 (10.6ms, 10.3us/step) removed the acquire
// invalidates but kept a RELEASE atomic flag store per block-step, which
// lowers to buffer_wbl2 (whole-L2 dirty walk) x 128 blocks x 1024 steps.
// MfmaUtil 3.6% => ~88% of each step was still sync machinery.
// Now there is NO cache-maintenance op in the binary at all:
//  - h stores are write-through to LLC: global_store_short ... sc0 sc1.
//    L2 never holds dirty h lines -> nothing to write back.
//  - release = explicit per-wave s_waitcnt vmcnt(0) (sc0 sc1 store acks
//    at its coherence point = LLC) -> __syncthreads -> tid0 plain
//    sc0 sc1 flag store. h-at-LLC strictly precedes flag-at-LLC.
//  - consumer unchanged: relaxed flag poll + LLC-direct (sc0 sc1)
//    pipelined h loads with counted vmcnt waits.
// x / weights stay warm in L2 forever (read-only, never invalidated).
// Numerics identical to R8 (validated there: absmax 1.95e-3).

#define Bsz 128
#define Tsz 1024
#define Isz 256
#define Hsz 512
#define NBLK 128
#define NTHREADS 256

typedef __attribute__((ext_vector_type(8))) short short8;
typedef __attribute__((ext_vector_type(4))) float float4v;

__device__ __forceinline__ float b2f(unsigned short u) {
  union { float f; unsigned int i; } v; v.i = ((unsigned int)u) << 16; return v.f;
}
__device__ __forceinline__ unsigned short f2b(float f) {
  unsigned int u = __float_as_uint(f);
  return (unsigned short)((u + 0x7fffu + ((u >> 16) & 1u)) >> 16);
}
__device__ __forceinline__ float sigmf(float x) { return 1.0f / (1.0f + __expf(-x)); }
__device__ __forceinline__ float tanhf_fast(float x) {
  float e = __expf(-2.0f * fabsf(x));
  float t = (1.0f - e) / (1.0f + e);
  return copysignf(t, x);
}
__device__ __forceinline__ short8 cvt8(const float* p) {
  float4 u = *(const float4*)(p);
  float4 v = *(const float4*)(p + 4);
  short8 r;
  r[0] = (short)f2b(u.x); r[1] = (short)f2b(u.y);
  r[2] = (short)f2b(u.z); r[3] = (short)f2b(u.w);
  r[4] = (short)f2b(v.x); r[5] = (short)f2b(v.y);
  r[6] = (short)f2b(v.z); r[7] = (short)f2b(v.w);
  return r;
}

#define MFMA(A, B, C) __builtin_amdgcn_mfma_f32_16x16x32_bf16((A), (B), (C), 0, 0, 0)

// LLC-direct 16B load: bypasses L1 and the (possibly stale) per-XCD L2.
#define LLD(dst, base, OFFB)                                              \
  asm volatile("global_load_dwordx4 %0, %1, off offset:" OFFB " sc0 sc1"  \
               : "=v"(dst) : "v"(base))

// Issue one 4-ks chunk: 4x hi + 4x lo (8 loads, 128B/lane).
#define LCHUNK(c, O0, O1, O2, O3)                                         \
  LLD(hb[4 * (c) + 0], hh, O0); LLD(hb[4 * (c) + 1], hh, O1);             \
  LLD(hb[4 * (c) + 2], hh, O2); LLD(hb[4 * (c) + 3], hh, O3);             \
  LLD(lb[4 * (c) + 0], hl, O0); LLD(lb[4 * (c) + 1], hl, O1);             \
  LLD(lb[4 * (c) + 2], hl, O2); LLD(lb[4 * (c) + 3], hl, O3)

// LLC write-through 2-byte store (no dirty L2 line created).
#define WTS(addr, val)                                                    \
  asm volatile("global_store_short %0, %1, off sc0 sc1"                   \
               :: "v"(addr), "v"(val) : "memory")

// One K-slice of the h-part. Main terms into a0m/a1m, compensation terms
// into a0c/a1c (halves the dependent chain vs single accumulator).
#define HSTEP(ks) do {                                                    \
    short8 bh0 = whi[(8 + (ks)) * 64 + lane];                             \
    short8 bh1 = whi[1536 + (8 + (ks)) * 64 + lane];                      \
    short8 bl0 = wlo[(ks) * 64 + lane];                                   \
    short8 bl1 = wlo[1024 + (ks) * 64 + lane];                            \
    a0m = MFMA(hb[(ks)], bh0, a0m);                                       \
    a1m = MFMA(hb[(ks)], bh1, a1m);                                       \
    a0c = MFMA(hb[(ks)], bl0, a0c);                                       \
    a1c = MFMA(hb[(ks)], bl1, a1c);                                       \
    a0c = MFMA(lb[(ks)], bh0, a0c);                                       \
    a1c = MFMA(lb[(ks)], bh1, a1c);                                       \
  } while (0)

__global__ __launch_bounds__(NTHREADS, 1) void lstm_persistent(
    const float* __restrict__ x,
    const float* __restrict__ wih,
    const float* __restrict__ whh,
    const float* __restrict__ bih,
    const float* __restrict__ bhh,
    float* __restrict__ out,
    unsigned short* __restrict__ hhi0,
    unsigned short* __restrict__ hhi1,
    unsigned short* __restrict__ hlo0,
    unsigned short* __restrict__ hlo1,
    unsigned int* __restrict__ flags)   // 2 domains x 64 flags x 32 dwords
{
  __shared__ short8 whi[2 * 24 * 64];  // 48 KB: W_ih|W_hh hi
  __shared__ short8 wlo[2 * 16 * 64];  // 32 KB: W_hh lo

  const int tid  = threadIdx.x;
  const int blk  = blockIdx.x;
  const int hb_g = blk & 63;   // hidden group: units j0..j0+7; also idx in domain
  const int bb   = blk >> 6;   // batch half == sync domain
  const int j0   = hb_g * 8;
  const int rb   = bb * 64;
  const int w    = tid >> 6;
  const int lane = tid & 63;
  const int l15  = lane & 15;
  const int kq   = lane >> 4;

  unsigned int* dfl = flags + (size_t)bb * 64 * 32;  // this domain's flags
  unsigned int* myf = dfl + (size_t)hb_g * 32;       // this block's flag

  // ---- prepack W into LDS as bf16 MFMA B-fragments (hi + lo for W_hh) ----
  for (int idx = tid; idx < 3072; idx += NTHREADS) {
    int nt  = (idx >= 1536) ? 1 : 0;
    int rem = idx - nt * 1536;
    int ks  = rem >> 6;
    int ln  = rem & 63;
    int col = nt * 16 + (ln & 15);
    int k   = ks * 32 + (ln >> 4) * 8;
    int grow = (col >> 3) * Hsz + j0 + (col & 7);
    const float* src = (ks < 8) ? (wih + (size_t)grow * Isz + k)
                                : (whh + (size_t)grow * Hsz + (k - Isz));
    float wv[8];
#pragma unroll
    for (int j = 0; j < 8; ++j) wv[j] = src[j];
    short8 hi;
#pragma unroll
    for (int j = 0; j < 8; ++j) hi[j] = (short)f2b(wv[j]);
    whi[idx] = hi;
    if (ks >= 8) {
      short8 lo;
#pragma unroll
      for (int j = 0; j < 8; ++j)
        lo[j] = (short)f2b(wv[j] - b2f((unsigned short)hi[j]));
      wlo[nt * 1024 + (ks - 8) * 64 + ln] = lo;
    }
  }

  const int colA = l15;
  const int colB = 16 + l15;
  const int gA = (colA >> 3) * Hsz + j0 + (colA & 7);
  const int gB = (colB >> 3) * Hsz + j0 + (colB & 7);
  const float biasA = bih[gA] + bhh[gA];
  const float biasB = bih[gB] + bhh[gB];

  __syncthreads();

  const int arow = rb + w * 16 + l15;
  const float* xrow = x + (size_t)arow * (Tsz * Isz) + kq * 8;

  float cst[4] = {0.f, 0.f, 0.f, 0.f};
  const int rbase0 = rb + w * 16 + kq * 4;
  const int gcol   = j0 + (l15 & 7);

  for (int t = 0; t < Tsz; ++t) {
    float4v a0m = {0.f, 0.f, 0.f, 0.f};
    float4v a1m = {0.f, 0.f, 0.f, 0.f};
    float4v a0c = {0.f, 0.f, 0.f, 0.f};
    float4v a1c = {0.f, 0.f, 0.f, 0.f};
    const float* xp = xrow + (size_t)t * Isz;

    // ---- x-part first: independent of other blocks (hides barrier skew).
    // Cached loads: with no cache-maintenance ops these stay L2-warm. ----
#pragma unroll
    for (int ks = 0; ks < 8; ++ks) {
      short8 av = cvt8(xp + ks * 32);
      short8 b0 = whi[ks * 64 + lane];
      short8 b1 = whi[1536 + ks * 64 + lane];
      a0m = MFMA(av, b0, a0m);
      a1m = MFMA(av, b1, a1m);
    }

    // ---- wait for step-t h from all blocks in this domain (relaxed poll,
    // no acquire fence: the h loads below bypass L1/L2 by construction) ----
    if (t > 0) {
      if (tid < 64) {
        const unsigned int* f = dfl + (size_t)tid * 32;
        int guard = 0;
        while (__hip_atomic_load(f, __ATOMIC_RELAXED, __HIP_MEMORY_SCOPE_AGENT)
               < (unsigned)t) {
          __builtin_amdgcn_s_sleep(1);
          if (++guard > (1 << 26)) break;  // fail loud, not hang
        }
      }
      __syncthreads();
    }

    const unsigned short* hh = ((t & 1) ? hhi1 : hhi0) + (size_t)arow * Hsz + kq * 8;
    const unsigned short* hl = ((t & 1) ? hlo1 : hlo0) + (size_t)arow * Hsz + kq * 8;

    // ---- issue all 32 LLC loads (512B/lane), then consume in 4 chunks
    // with counted waits. In-order vmcnt retirement makes the counts
    // exact; barriers on both sides keep foreign VMEM out of the window. ----
    short8 hb[16], lb[16];
    LCHUNK(0, "0",   "64",  "128", "192");
    LCHUNK(1, "256", "320", "384", "448");
    LCHUNK(2, "512", "576", "640", "704");
    LCHUNK(3, "768", "832", "896", "960");

    asm volatile("s_waitcnt vmcnt(24)");
    __builtin_amdgcn_sched_barrier(0x104);  // allow DS_READ+SALU across, pin MFMA
    HSTEP(0); HSTEP(1); HSTEP(2); HSTEP(3);
    asm volatile("s_waitcnt vmcnt(16)");
    __builtin_amdgcn_sched_barrier(0x104);
    HSTEP(4); HSTEP(5); HSTEP(6); HSTEP(7);
    asm volatile("s_waitcnt vmcnt(8)");
    __builtin_amdgcn_sched_barrier(0x104);
    HSTEP(8); HSTEP(9); HSTEP(10); HSTEP(11);
    asm volatile("s_waitcnt vmcnt(0)");
    __builtin_amdgcn_sched_barrier(0x104);
    HSTEP(12); HSTEP(13); HSTEP(14); HSTEP(15);

    // bias + gate exchange (i<->f, g<->o live in lanes l and l^8)
    float v0[4], v1[4], p0[4], p1[4];
#pragma unroll
    for (int r = 0; r < 4; ++r) {
      v0[r] = a0m[r] + a0c[r] + biasA;
      v1[r] = a1m[r] + a1c[r] + biasB;
      p0[r] = __shfl_xor(v0[r], 8, 64);
      p1[r] = __shfl_xor(v1[r], 8, 64);
    }
    if (l15 < 8) {
      unsigned short* dhh = (t & 1) ? hhi0 : hhi1;
      unsigned short* dhl = (t & 1) ? hlo0 : hlo1;
#pragma unroll
      for (int r = 0; r < 4; ++r) {
        float ig = sigmf(v0[r]);
        float fg = sigmf(p0[r]);
        float gg = tanhf_fast(v1[r]);
        float og = sigmf(p1[r]);
        float c  = fg * cst[r] + ig * gg;
        cst[r] = c;
        float hv = og * tanhf_fast(c);
        int off = (rbase0 + r) * Hsz + gcol;
        if (t == Tsz - 1) {
          out[off] = hv;                    // fp32 output (cached; kernel-end flush)
        } else {
          unsigned short hb16 = f2b(hv);
          unsigned short lo16 = f2b(hv - b2f(hb16));
          // write-through to LLC: no dirty L2 lines -> no wbl2 needed ever
          WTS(dhh + off, (unsigned int)hb16);
          WTS(dhl + off, (unsigned int)lo16);
        }
      }
    }

    if (t != Tsz - 1) {
      // release without cache maintenance:
      // each wave drains its own sc0 sc1 stores (acked at LLC) ...
      asm volatile("s_waitcnt vmcnt(0)" ::: "memory");
      __syncthreads();   // ... then all waves rendezvous ...
      if (tid == 0) {
        // ... then the flag goes to LLC strictly after all h data.
        unsigned int fv = (unsigned int)(t + 1);
        asm volatile("global_store_dword %0, %1, off sc0 sc1"
                     :: "v"(myf), "v"(fv) : "memory");
      }
      // no trailing syncthreads: next iteration's poll has its own barrier
    }
  }
}

extern "C" void kernel_launch(void* const* d_in, const int* in_sizes, int n_in,
                              void* d_out, int out_size, void* d_ws, size_t ws_size,
                              hipStream_t stream) {
  if (n_in < 5) return;
  long long s0 = in_sizes[0], s1 = in_sizes[1], s2 = in_sizes[2],
            s3 = in_sizes[3], s4 = in_sizes[4];
  if (!(s1 > 0 && s3 > 0 && s0 == 64 * s1 && s2 == 2 * s1 &&
        s1 == 256 * s3 && s3 == s4)) return;

  const float* x   = (const float*)d_in[0];
  const float* wih = (const float*)d_in[1];
  const float* whh = (const float*)d_in[2];
  const float* bih = (const float*)d_in[3];
  const float* bhh = (const float*)d_in[4];
  float* out = (float*)d_out;

  char* ws = (char*)d_ws;
  const size_t FLAGS_BYTES = 2 * 64 * 32 * 4;  // 16 KB
  const size_t HB = (size_t)Bsz * Hsz * 2;     // 128 KB per bf16 h buffer
  unsigned int*   flags = (unsigned int*)ws;
  unsigned short* hhi0 = (unsigned short*)(ws + FLAGS_BYTES);
  unsigned short* hhi1 = (unsigned short*)(ws + FLAGS_BYTES + HB);
  unsigned short* hlo0 = (unsigned short*)(ws + FLAGS_BYTES + 2 * HB);
  unsigned short* hlo1 = (unsigned short*)(ws + FLAGS_BYTES + 3 * HB);

  hipMemsetAsync(d_ws, 0, FLAGS_BYTES + 4 * HB, stream);

  hipLaunchKernelGGL(lstm_persistent, dim3(NBLK), dim3(NTHREADS), 0, stream,
                     x, wih, whh, bih, bhh, out, hhi0, hhi1, hlo0, hlo1, flags);
}

// Round 3
// 8073.078 us; speedup vs baseline: 1.6378x; 1.0469x over previous
//
#include <hip/hip_runtime.h>
#include <stdint.h>

// LSTM final-h. B=128, T=1024, I=256, H=512. Inputs fp32, output fp32.
// R10: overlap the serial latency phases. R9 (8.45ms, 8.2us/step) had
// MfmaUtil 4.6%: step chain = x HBM loads (serial, ~1.5-2us) + poll +
// h LLC loads + MFMA + store-ack, all sequential. Now:
//  - x(t+1) prefetched into VGPRs during step t: 16 volatile-asm cached
//    dwordx4 issued AFTER the 32 h LLC loads. In-order vmcnt retirement
//    keeps chunk gating exact with constants 40/32/24/16 (8 h-loads per
//    chunk + 16 x-loads at FIFO tail). Release vmcnt(0) drains x free;
//    next step's x-part reads registers with no wait.
//  - per-wave flags (4 dwords/block line): each wave vmcnt(0)-drains its
//    own WT stores then signals; producer-side __syncthreads removed.
//    Consumer polls one dwordx4 sc0 sc1 per block and min4-checks.
//  - h buffers interleaved [row][group][hi8|lo8]: hi/lo pair shares one
//    64B segment -> half the distinct LLC lines on store and load paths.
// Still zero cache-maintenance ops (R9 invariant): h stores are WT
// (sc0 sc1), h loads LLC-direct (sc0 sc1), x/weights L2-cached forever.
// Numerics bit-identical to R9 (absmax 1.95e-3 there).

#define Bsz 128
#define Tsz 1024
#define Isz 256
#define Hsz 512
#define NBLK 128
#define NTHREADS 256

typedef __attribute__((ext_vector_type(8))) short short8;
typedef __attribute__((ext_vector_type(4))) float float4v;
typedef __attribute__((ext_vector_type(4))) unsigned int uint4v;

__device__ __forceinline__ float b2f(unsigned short u) {
  union { float f; unsigned int i; } v; v.i = ((unsigned int)u) << 16; return v.f;
}
__device__ __forceinline__ unsigned short f2b(float f) {
  unsigned int u = __float_as_uint(f);
  return (unsigned short)((u + 0x7fffu + ((u >> 16) & 1u)) >> 16);
}
__device__ __forceinline__ float sigmf(float x) { return 1.0f / (1.0f + __expf(-x)); }
__device__ __forceinline__ float tanhf_fast(float x) {
  float e = __expf(-2.0f * fabsf(x));
  float t = (1.0f - e) / (1.0f + e);
  return copysignf(t, x);
}
// convert 8 fp32 (two float4v regs) -> short8 bf16 fragment
__device__ __forceinline__ short8 cvt8r(float4v u, float4v v) {
  short8 r;
  r[0] = (short)f2b(u[0]); r[1] = (short)f2b(u[1]);
  r[2] = (short)f2b(u[2]); r[3] = (short)f2b(u[3]);
  r[4] = (short)f2b(v[0]); r[5] = (short)f2b(v[1]);
  r[6] = (short)f2b(v[2]); r[7] = (short)f2b(v[3]);
  return r;
}

#define MFMA(A, B, C) __builtin_amdgcn_mfma_f32_16x16x32_bf16((A), (B), (C), 0, 0, 0)

// LLC-direct 16B load (bypass L1/L2 - the coherent h path).
#define LLD(dst, base, OFFB)                                              \
  asm volatile("global_load_dwordx4 %0, %1, off offset:" OFFB " sc0 sc1"  \
               : "=v"(dst) : "v"(base))

// Cached 16B load (x prefetch). Volatile asm: must stay AFTER the h loads
// in the vmcnt FIFO so the counted chunk waits stay exact.
#define XLD(dst, base, OFFB)                                              \
  asm volatile("global_load_dwordx4 %0, %1, off offset:" OFFB             \
               : "=v"(dst) : "v"(base))

// hi/lo pair for one K-slice: same 64B segment (interleaved layout).
#define LPAIR(ks, OH, OL)                                                 \
  LLD(hbv[ks], hbase, OH); LLD(lbv[ks], hbase, OL)

// issue all 16 x-prefetch loads for one timestep (byte offsets ks*128+{0,16})
#define XCHUNK(xp)                                                        \
  XLD(xf[0],  xp, "0");   XLD(xf[1],  xp, "16");                          \
  XLD(xf[2],  xp, "128"); XLD(xf[3],  xp, "144");                         \
  XLD(xf[4],  xp, "256"); XLD(xf[5],  xp, "272");                         \
  XLD(xf[6],  xp, "384"); XLD(xf[7],  xp, "400");                         \
  XLD(xf[8],  xp, "512"); XLD(xf[9],  xp, "528");                         \
  XLD(xf[10], xp, "640"); XLD(xf[11], xp, "656");                         \
  XLD(xf[12], xp, "768"); XLD(xf[13], xp, "784");                         \
  XLD(xf[14], xp, "896"); XLD(xf[15], xp, "912")

// LLC write-through 2-byte store (no dirty L2 line created).
#define WTS(addr, val)                                                    \
  asm volatile("global_store_short %0, %1, off sc0 sc1"                   \
               :: "v"(addr), "v"(val) : "memory")

#define VMWAIT(N) asm volatile("s_waitcnt vmcnt(" #N ")")

// One K-slice of the h-part. Main terms into a0m/a1m, compensation terms
// into a0c/a1c (halves the dependent chain vs single accumulator).
#define HSTEP(ks) do {                                                    \
    short8 bh0 = whi[(8 + (ks)) * 64 + lane];                             \
    short8 bh1 = whi[1536 + (8 + (ks)) * 64 + lane];                      \
    short8 bl0 = wlo[(ks) * 64 + lane];                                   \
    short8 bl1 = wlo[1024 + (ks) * 64 + lane];                            \
    a0m = MFMA(hbv[(ks)], bh0, a0m);                                      \
    a1m = MFMA(hbv[(ks)], bh1, a1m);                                      \
    a0c = MFMA(hbv[(ks)], bl0, a0c);                                      \
    a1c = MFMA(hbv[(ks)], bl1, a1c);                                      \
    a0c = MFMA(lbv[(ks)], bh0, a0c);                                      \
    a1c = MFMA(lbv[(ks)], bh1, a1c);                                      \
  } while (0)

__global__ __launch_bounds__(NTHREADS, 1) void lstm_persistent(
    const float* __restrict__ x,
    const float* __restrict__ wih,
    const float* __restrict__ whh,
    const float* __restrict__ bih,
    const float* __restrict__ bhh,
    float* __restrict__ out,
    unsigned short* __restrict__ hb0,   // interleaved hi/lo, parity-0 buffer
    unsigned short* __restrict__ hb1,   // parity-1 buffer
    unsigned int* __restrict__ flags)   // 2 domains x 64 blocks x 32 dwords
{
  __shared__ short8 whi[2 * 24 * 64];  // 48 KB: W_ih|W_hh hi
  __shared__ short8 wlo[2 * 16 * 64];  // 32 KB: W_hh lo

  const int tid  = threadIdx.x;
  const int blk  = blockIdx.x;
  const int hb_g = blk & 63;   // hidden group: units j0..j0+7; also idx in domain
  const int bb   = blk >> 6;   // batch half == sync domain
  const int j0   = hb_g * 8;
  const int rb   = bb * 64;
  const int w    = tid >> 6;
  const int lane = tid & 63;
  const int l15  = lane & 15;
  const int kq   = lane >> 4;

  unsigned int* dfl = flags + (size_t)bb * 64 * 32;  // this domain's flags
  unsigned int* myf = dfl + (size_t)hb_g * 32;       // this block's flag line

  // ---- prepack W into LDS as bf16 MFMA B-fragments (hi + lo for W_hh) ----
  for (int idx = tid; idx < 3072; idx += NTHREADS) {
    int nt  = (idx >= 1536) ? 1 : 0;
    int rem = idx - nt * 1536;
    int ks  = rem >> 6;
    int ln  = rem & 63;
    int col = nt * 16 + (ln & 15);
    int k   = ks * 32 + (ln >> 4) * 8;
    int grow = (col >> 3) * Hsz + j0 + (col & 7);
    const float* src = (ks < 8) ? (wih + (size_t)grow * Isz + k)
                                : (whh + (size_t)grow * Hsz + (k - Isz));
    float wv[8];
#pragma unroll
    for (int j = 0; j < 8; ++j) wv[j] = src[j];
    short8 hi;
#pragma unroll
    for (int j = 0; j < 8; ++j) hi[j] = (short)f2b(wv[j]);
    whi[idx] = hi;
    if (ks >= 8) {
      short8 lo;
#pragma unroll
      for (int j = 0; j < 8; ++j)
        lo[j] = (short)f2b(wv[j] - b2f((unsigned short)hi[j]));
      wlo[nt * 1024 + (ks - 8) * 64 + ln] = lo;
    }
  }

  const int colA = l15;
  const int colB = 16 + l15;
  const int gA = (colA >> 3) * Hsz + j0 + (colA & 7);
  const int gB = (colB >> 3) * Hsz + j0 + (colB & 7);
  const float biasA = bih[gA] + bhh[gA];
  const float biasB = bih[gB] + bhh[gB];

  __syncthreads();

  const int arow = rb + w * 16 + l15;
  const float* xrow = x + (size_t)arow * (Tsz * Isz) + kq * 8;

  // interleaved h row base (shorts): row*1024 + group(kq)*16; hi +0, lo +8
  const unsigned short* hR0 = hb0 + (size_t)arow * 1024 + kq * 16;
  const unsigned short* hR1 = hb1 + (size_t)arow * 1024 + kq * 16;

  float cst[4] = {0.f, 0.f, 0.f, 0.f};
  const int rbase0 = rb + w * 16 + kq * 4;

  // ---- prologue: prefetch x(0) into registers ----
  float4v xf[16];
  XCHUNK(xrow);
  asm volatile("s_waitcnt vmcnt(0)" ::: "memory");

  for (int t = 0; t < Tsz; ++t) {
    float4v a0m = {0.f, 0.f, 0.f, 0.f};
    float4v a1m = {0.f, 0.f, 0.f, 0.f};
    float4v a0c = {0.f, 0.f, 0.f, 0.f};
    float4v a1c = {0.f, 0.f, 0.f, 0.f};

    // ---- x-part from prefetched registers (no memory wait) ----
#pragma unroll
    for (int ks = 0; ks < 8; ++ks) {
      short8 av = cvt8r(xf[2 * ks], xf[2 * ks + 1]);
      short8 b0 = whi[ks * 64 + lane];
      short8 b1 = whi[1536 + ks * 64 + lane];
      a0m = MFMA(av, b0, a0m);
      a1m = MFMA(av, b1, a1m);
    }

    // ---- wait for step-t h from all blocks in this domain ----
    if (t > 0) {
      if (tid < 64) {
        const unsigned int* f = dfl + (size_t)tid * 32;
        int guard = 0;
        for (;;) {
          uint4v fv;
          asm volatile("global_load_dwordx4 %0, %1, off sc0 sc1\n\t"
                       "s_waitcnt vmcnt(0)"
                       : "=v"(fv) : "v"(f) : "memory");
          unsigned m0 = fv[0] < fv[1] ? fv[0] : fv[1];
          unsigned m1 = fv[2] < fv[3] ? fv[2] : fv[3];
          unsigned m  = m0 < m1 ? m0 : m1;
          if (m >= (unsigned)t) break;
          __builtin_amdgcn_s_sleep(1);
          if (++guard > (1 << 26)) break;  // fail loud, not hang
        }
      }
      __syncthreads();
    }

    // ---- issue 32 h LLC loads (hi/lo pairs share a 64B segment) ----
    const unsigned short* hbase = (t & 1) ? hR1 : hR0;
    short8 hbv[16], lbv[16];
    LPAIR(0,  "0",    "16");   LPAIR(1,  "128",  "144");
    LPAIR(2,  "256",  "272");  LPAIR(3,  "384",  "400");
    LPAIR(4,  "512",  "528");  LPAIR(5,  "640",  "656");
    LPAIR(6,  "768",  "784");  LPAIR(7,  "896",  "912");
    LPAIR(8,  "1024", "1040"); LPAIR(9,  "1152", "1168");
    LPAIR(10, "1280", "1296"); LPAIR(11, "1408", "1424");
    LPAIR(12, "1536", "1552"); LPAIR(13, "1664", "1680");
    LPAIR(14, "1792", "1808"); LPAIR(15, "1920", "1936");

    // ---- issue 16 x(t+1) cached loads at the FIFO tail: they retire
    // after all h loads, so chunk constants gate exactly on h chunks;
    // the release vmcnt(0) drains them for free. ----
    const float* xpn = xrow + (size_t)((t + 1 < Tsz) ? t + 1 : t) * Isz;
    XCHUNK(xpn);

    // ---- consume h in 4 chunks with counted waits (8 h-loads/chunk,
    // 16 x-loads always outstanding at the tail) ----
    VMWAIT(40);
    __builtin_amdgcn_sched_barrier(0x104);  // allow DS_READ+SALU, pin MFMA
    HSTEP(0); HSTEP(1); HSTEP(2); HSTEP(3);
    VMWAIT(32);
    __builtin_amdgcn_sched_barrier(0x104);
    HSTEP(4); HSTEP(5); HSTEP(6); HSTEP(7);
    VMWAIT(24);
    __builtin_amdgcn_sched_barrier(0x104);
    HSTEP(8); HSTEP(9); HSTEP(10); HSTEP(11);
    VMWAIT(16);
    __builtin_amdgcn_sched_barrier(0x104);
    HSTEP(12); HSTEP(13); HSTEP(14); HSTEP(15);

    // bias + gate exchange (i<->f, g<->o live in lanes l and l^8)
    float v0[4], v1[4], p0[4], p1[4];
#pragma unroll
    for (int r = 0; r < 4; ++r) {
      v0[r] = a0m[r] + a0c[r] + biasA;
      v1[r] = a1m[r] + a1c[r] + biasB;
      p0[r] = __shfl_xor(v0[r], 8, 64);
      p1[r] = __shfl_xor(v1[r], 8, 64);
    }
    if (l15 < 8) {
      unsigned short* dhb = ((t & 1) ? hb0 : hb1) + (size_t)0;  // next-parity buffer
#pragma unroll
      for (int r = 0; r < 4; ++r) {
        float ig = sigmf(v0[r]);
        float fg = sigmf(p0[r]);
        float gg = tanhf_fast(v1[r]);
        float og = sigmf(p1[r]);
        float c  = fg * cst[r] + ig * gg;
        cst[r] = c;
        float hv = og * tanhf_fast(c);
        if (t == Tsz - 1) {
          out[(rbase0 + r) * Hsz + j0 + l15] = hv;   // fp32 output
        } else {
          unsigned short hi16 = f2b(hv);
          unsigned short lo16 = f2b(hv - b2f(hi16));
          // interleaved layout: row*1024 + group(hb_g)*16 + elem; lo at +8
          unsigned short* p = dhb + (size_t)(rbase0 + r) * 1024 + hb_g * 16 + l15;
          WTS(p,     (unsigned int)hi16);
          WTS(p + 8, (unsigned int)lo16);
        }
      }
    }

    if (t != Tsz - 1) {
      // release per wave: drain own WT stores (+ x prefetch, long done),
      // then this wave's flag goes to LLC strictly after its h data.
      asm volatile("s_waitcnt vmcnt(0)" ::: "memory");
      if (lane == 0) {
        unsigned int fv = (unsigned int)(t + 1);
        asm volatile("global_store_dword %0, %1, off sc0 sc1"
                     :: "v"(myf + w), "v"(fv) : "memory");
      }
      // no producer-side syncthreads: consumer min4-checks all 4 wave flags
    }
  }
}

extern "C" void kernel_launch(void* const* d_in, const int* in_sizes, int n_in,
                              void* d_out, int out_size, void* d_ws, size_t ws_size,
                              hipStream_t stream) {
  if (n_in < 5) return;
  long long s0 = in_sizes[0], s1 = in_sizes[1], s2 = in_sizes[2],
            s3 = in_sizes[3], s4 = in_sizes[4];
  if (!(s1 > 0 && s3 > 0 && s0 == 64 * s1 && s2 == 2 * s1 &&
        s1 == 256 * s3 && s3 == s4)) return;

  const float* x   = (const float*)d_in[0];
  const float* wih = (const float*)d_in[1];
  const float* whh = (const float*)d_in[2];
  const float* bih = (const float*)d_in[3];
  const float* bhh = (const float*)d_in[4];
  float* out = (float*)d_out;

  char* ws = (char*)d_ws;
  const size_t FLAGS_BYTES = 2 * 64 * 32 * 4;      // 16 KB
  const size_t HB = (size_t)Bsz * 1024 * 2;        // 256 KB per interleaved buffer
  unsigned int*   flags = (unsigned int*)ws;
  unsigned short* hb0 = (unsigned short*)(ws + FLAGS_BYTES);
  unsigned short* hb1 = (unsigned short*)(ws + FLAGS_BYTES + HB);

  hipMemsetAsync(d_ws, 0, FLAGS_BYTES + 2 * HB, stream);

  hipLaunchKernelGGL(lstm_persistent, dim3(NBLK), dim3(NTHREADS), 0, stream,
                     x, wih, whh, bih, bhh, out, hb0, hb1, flags);
}

// Round 4
// 6000.859 us; speedup vs baseline: 2.2033x; 1.3453x over previous
//
#include <hip/hip_runtime.h>
#include <stdint.h>

// LSTM final-h. B=128, T=1024, I=256, H=512. Inputs fp32, output fp32.
// R11: structural rework — W in REGISTERS, small domains.
// R8-R10 removed cache-maintenance/fence overheads (13.2->8.07ms) but the
// ~7us/step core remained: with W in LDS (80KB => 32 gate-cols/block),
// domains were pinned at 64 blocks x 64 rows, so every step all 64 blocks
// re-read the domain's FULL h LLC-direct: 16 MB/step of synchronized
// uncacheable broadcast + a 64-wide rendezvous. Now:
//  - 512-thread blocks (8 waves, 2/SIMD). Each wave holds its 16 gate-cols
//    of W_ih (hi) + W_hh (hi+lo) as MFMA B-fragments in VGPRs (~160 regs).
//    LDS holds only staged activations (48 KB).
//  - 8 domains x 16 blocks x 16 batch rows. Per step each block stages
//    h[16][512] (hi|lo packed dwords, 32 KB) into LDS once; all 8 waves
//    consume from LDS. Device h-broadcast: 16 MB -> 4 MB/step.
//  - producer: 4 packed global_store_dword sc0 sc1 per active lane
//    (was 8 scalar shorts); per-wave release flag after vmcnt(0) drain.
//    Flags spread across 256B-strided lines (less LLC line contention).
//  - consumer: wave0 polls the domain's 128 wave-flags (dwordx2/lane),
//    barrier releases; h stage loads are LLC-direct (sc0 sc1).
//  - x(t+1) prefetched to regs at step top, staged to LDS bf16 planes.
//  - still ZERO cache-maintenance ops (no buffer_inv / buffer_wbl2).
// Numerics: identical MFMA set per output column in identical order ->
// bit-identical to R10 (absmax 1.95e-3 there).

#define Bsz 128
#define Tsz 1024
#define Isz 256
#define Hsz 512
#define NBLK 128      // 8 domains x 16 blocks
#define NTHREADS 512  // 8 waves

typedef __attribute__((ext_vector_type(8))) short short8;
typedef __attribute__((ext_vector_type(4))) float float4v;
typedef __attribute__((ext_vector_type(4))) unsigned int uint4v;
typedef __attribute__((ext_vector_type(2))) unsigned int uint2v;

__device__ __forceinline__ float b2f(unsigned short u) {
  union { float f; unsigned int i; } v; v.i = ((unsigned int)u) << 16; return v.f;
}
__device__ __forceinline__ unsigned short f2b(float f) {
  unsigned int u = __float_as_uint(f);
  return (unsigned short)((u + 0x7fffu + ((u >> 16) & 1u)) >> 16);
}
__device__ __forceinline__ float sigmf(float x) { return 1.0f / (1.0f + __expf(-x)); }
__device__ __forceinline__ float tanhf_fast(float x) {
  float e = __expf(-2.0f * fabsf(x));
  float t = (1.0f - e) / (1.0f + e);
  return copysignf(t, x);
}
__device__ __forceinline__ short8 cvt8r(float4v u, float4v v) {
  short8 r;
  r[0] = (short)f2b(u[0]); r[1] = (short)f2b(u[1]);
  r[2] = (short)f2b(u[2]); r[3] = (short)f2b(u[3]);
  r[4] = (short)f2b(v[0]); r[5] = (short)f2b(v[1]);
  r[6] = (short)f2b(v[2]); r[7] = (short)f2b(v[3]);
  return r;
}

#define MFMA(A, B, C) __builtin_amdgcn_mfma_f32_16x16x32_bf16((A), (B), (C), 0, 0, 0)

// LLC-direct 16B load (coherent h path; bypass L1/L2).
#define LLD(dst, base, OFFB)                                              \
  asm volatile("global_load_dwordx4 %0, %1, off offset:" OFFB " sc0 sc1"  \
               : "=v"(dst) : "v"(base))
// Cached 16B load, pinned at issue point (x prefetch).
#define XLD(dst, base, OFFB)                                              \
  asm volatile("global_load_dwordx4 %0, %1, off offset:" OFFB             \
               : "=v"(dst) : "v"(base))
#define VM0 asm volatile("s_waitcnt vmcnt(0)" ::: "memory")

__global__ __launch_bounds__(NTHREADS, 2) void lstm_persistent(
    const float* __restrict__ x,
    const float* __restrict__ wih,
    const float* __restrict__ whh,
    const float* __restrict__ bih,
    const float* __restrict__ bhh,
    float* __restrict__ out,
    unsigned int* __restrict__ hb0,     // h packed (hi | lo<<16), parity 0: [128][512] dwords
    unsigned int* __restrict__ hb1,     // parity 1
    unsigned int* __restrict__ flags)   // 8 domains x (16 blocks x 256B chunk: 8 wave-dwords)
{
  __shared__ short8 hhi_pl[16 * 64];   // 16 KB: h hi-plane, [row][unit-chunk swz]
  __shared__ short8 hlo_pl[16 * 64];   // 16 KB: h lo-plane
  __shared__ short8 x_pl[2][16 * 32];  // 16 KB: x bf16 planes, double-buffered

  const int tid  = threadIdx.x;
  const int wid  = tid >> 6;
  const int lane = tid & 63;
  const int l15  = lane & 15;
  const int kq   = lane >> 4;
  const int blk  = blockIdx.x;
  const int dom  = blk >> 4;   // 8 domains (16 batch rows each)
  const int bi   = blk & 15;   // block-in-domain: units bi*32 .. bi*32+31
  const int qg   = l15 >> 2;   // gate index 0..3 (i,f,g,o)
  const int ug   = l15 & 3;    // unit-within-4
  const int col  = qg * Hsz + bi * 32 + wid * 4 + ug;  // gate column 0..2047
  const int rowbase = dom * 16;

  // ---- W into registers as B-fragments (one-time prologue) ----
  short8 wx[8], whhhi[16], whhlo[16];
  {
    const float* p = wih + (size_t)col * Isz + kq * 8;
#pragma unroll
    for (int ks = 0; ks < 8; ++ks) {
      float4v u0 = *(const float4v*)(p + ks * 32);
      float4v u1 = *(const float4v*)(p + ks * 32 + 4);
      wx[ks] = cvt8r(u0, u1);
    }
  }
  {
    const float* p = whh + (size_t)col * Hsz + kq * 8;
#pragma unroll
    for (int ks = 0; ks < 16; ++ks) {
      float4v u0 = *(const float4v*)(p + ks * 32);
      float4v u1 = *(const float4v*)(p + ks * 32 + 4);
      short8 hi = cvt8r(u0, u1);
      short8 lo;
#pragma unroll
      for (int e = 0; e < 4; ++e) {
        lo[e]     = (short)f2b(u0[e] - b2f((unsigned short)hi[e]));
        lo[e + 4] = (short)f2b(u1[e] - b2f((unsigned short)hi[e + 4]));
      }
      whhhi[ks] = hi; whhlo[ks] = lo;
    }
  }
  const float biasC = bih[col] + bhh[col];

  // flags: dom*1024 + bi*64 + wid (dwords); 256B per block chunk
  unsigned int* myf = flags + dom * 1024 + bi * 64 + wid;
  const unsigned int* pollp = flags + dom * 1024 + (lane >> 2) * 64 + (lane & 3) * 2;

  // staging roles: wave wid stages rows {2wid, 2wid+1}; lane covers 16 units
  const int srow = 2 * wid + (lane >> 5);   // 0..15 (local row)
  const int schk = lane & 31;               // 8-unit chunk pairs: units schk*16..+15
  const int ssw  = srow & 7;
  const float* xsrc0 = x + (size_t)(rowbase + srow) * (Tsz * Isz) + schk * 8;

  // ---- prologue: stage x(0) ----
  {
    float4v u0, u1;
    XLD(u0, xsrc0, "0"); XLD(u1, xsrc0, "16");
    VM0;
    x_pl[0][srow * 32 + (schk ^ ssw)] = cvt8r(u0, u1);
  }
  __syncthreads();

  float cst[4] = {0.f, 0.f, 0.f, 0.f};
  const int hrow0 = rowbase + kq * 4;           // first acc row (global)
  const int hunit = bi * 32 + wid * 4 + ug;     // h unit (valid for qg==0 lanes)

  for (int t = 0; t < Tsz; ++t) {
    const int par = t & 1;

    // ---- issue x(t+1) prefetch (retires during poll/stage) ----
    float4v xu0, xu1;
    const int tn = (t + 1 < Tsz) ? t + 1 : t;
    {
      const float* xp = xsrc0 + (size_t)tn * Isz;
      XLD(xu0, xp, "0"); XLD(xu1, xp, "16");
    }

    // ---- x-part MFMAs from LDS plane (independent of other blocks) ----
    float4v accm = {0.f, 0.f, 0.f, 0.f};
    float4v accc = {0.f, 0.f, 0.f, 0.f};
#pragma unroll
    for (int ks = 0; ks < 8; ++ks) {
      short8 xa = x_pl[par][l15 * 32 + ((ks * 4 + kq) ^ (l15 & 7))];
      accm = MFMA(xa, wx[ks], accm);
    }

    // ---- wave0 polls all 128 wave-flags of this domain ----
    if (t > 0 && wid == 0) {
      int guard = 0;
      for (;;) {
        uint2v fv;
        asm volatile("global_load_dwordx2 %0, %1, off sc0 sc1\n\t"
                     "s_waitcnt vmcnt(0)"
                     : "=v"(fv) : "v"(pollp) : "memory");
        unsigned m = fv[0] < fv[1] ? fv[0] : fv[1];
        if (__all(m >= (unsigned)t)) break;
        __builtin_amdgcn_s_sleep(1);
        if (++guard > (1 << 26)) break;  // fail loud, not hang
      }
    }
    __syncthreads();  // barrier1: h(t) globally visible; LDS planes reusable

    // ---- stage x(t+1) into the other plane (loads long since retired) ----
    VM0;
    if (t + 1 < Tsz)
      x_pl[par ^ 1][srow * 32 + (schk ^ ssw)] = cvt8r(xu0, xu1);

    // ---- stage h(t): 32 KB/block LLC-direct, split into hi/lo planes ----
    {
      const unsigned int* hsrc =
          (par ? hb1 : hb0) + (size_t)(rowbase + srow) * Hsz + schk * 16;
      uint4v d0, d1, d2, d3;
      LLD(d0, hsrc, "0");  LLD(d1, hsrc, "16");
      LLD(d2, hsrc, "32"); LLD(d3, hsrc, "48");
      VM0;
      short8 h0, h1, l0, l1;
#pragma unroll
      for (int e = 0; e < 4; ++e) {
        h0[e]     = (short)(d0[e] & 0xffffu); l0[e]     = (short)(d0[e] >> 16);
        h0[e + 4] = (short)(d1[e] & 0xffffu); l0[e + 4] = (short)(d1[e] >> 16);
        h1[e]     = (short)(d2[e] & 0xffffu); l1[e]     = (short)(d2[e] >> 16);
        h1[e + 4] = (short)(d3[e] & 0xffffu); l1[e + 4] = (short)(d3[e] >> 16);
      }
      const int c0 = schk * 2;
      hhi_pl[srow * 64 + ((c0)     ^ ssw)] = h0;
      hhi_pl[srow * 64 + ((c0 + 1) ^ ssw)] = h1;
      hlo_pl[srow * 64 + ((c0)     ^ ssw)] = l0;
      hlo_pl[srow * 64 + ((c0 + 1) ^ ssw)] = l1;
    }
    __syncthreads();  // barrier2: planes ready

    // ---- h-part MFMAs (W from registers, A from LDS) ----
#pragma unroll
    for (int ks = 0; ks < 16; ++ks) {
      const int ci = l15 * 64 + ((ks * 4 + kq) ^ (l15 & 7));
      short8 ha = hhi_pl[ci];
      short8 la = hlo_pl[ci];
      accm = MFMA(ha, whhhi[ks], accm);
      accc = MFMA(ha, whhlo[ks], accc);
      accc = MFMA(la, whhhi[ks], accc);
    }

    // ---- gates: lanes hold (gate qg, unit), exchange via shfl_xor ----
    float v[4], vf[4], vg[4], vo[4];
#pragma unroll
    for (int r = 0; r < 4; ++r) {
      v[r]  = accm[r] + accc[r] + biasC;
      vf[r] = __shfl_xor(v[r], 4, 64);
      vg[r] = __shfl_xor(v[r], 8, 64);
      vo[r] = __shfl_xor(v[r], 12, 64);
    }
    if (qg == 0) {
      unsigned int* hdst = (par ? hb0 : hb1) + (size_t)hrow0 * Hsz + hunit;
#pragma unroll
      for (int r = 0; r < 4; ++r) {
        float ig = sigmf(v[r]);
        float fg = sigmf(vf[r]);
        float gg = tanhf_fast(vg[r]);
        float og = sigmf(vo[r]);
        float c  = fg * cst[r] + ig * gg;
        cst[r] = c;
        float hv = og * tanhf_fast(c);
        if (t == Tsz - 1) {
          out[(size_t)(hrow0 + r) * Hsz + hunit] = hv;   // fp32 output
        } else {
          unsigned short hi16 = f2b(hv);
          unsigned short lo16 = f2b(hv - b2f(hi16));
          unsigned int pk = (unsigned int)hi16 | ((unsigned int)lo16 << 16);
          unsigned int* pp = hdst + (size_t)r * Hsz;
          asm volatile("global_store_dword %0, %1, off sc0 sc1"
                       :: "v"(pp), "v"(pk) : "memory");
        }
      }
    }

    if (t != Tsz - 1) {
      // per-wave release: drain own WT stores (acked at LLC), then flag.
      VM0;
      if (lane == 0) {
        unsigned int fv = (unsigned)(t + 1);
        asm volatile("global_store_dword %0, %1, off sc0 sc1"
                     :: "v"(myf), "v"(fv) : "memory");
      }
    }
  }
}

extern "C" void kernel_launch(void* const* d_in, const int* in_sizes, int n_in,
                              void* d_out, int out_size, void* d_ws, size_t ws_size,
                              hipStream_t stream) {
  if (n_in < 5) return;
  long long s0 = in_sizes[0], s1 = in_sizes[1], s2 = in_sizes[2],
            s3 = in_sizes[3], s4 = in_sizes[4];
  if (!(s1 > 0 && s3 > 0 && s0 == 64 * s1 && s2 == 2 * s1 &&
        s1 == 256 * s3 && s3 == s4)) return;

  const float* x   = (const float*)d_in[0];
  const float* wih = (const float*)d_in[1];
  const float* whh = (const float*)d_in[2];
  const float* bih = (const float*)d_in[3];
  const float* bhh = (const float*)d_in[4];
  float* out = (float*)d_out;

  char* ws = (char*)d_ws;
  const size_t FLAGS_BYTES = 8 * 4096;             // 32 KB (8 domains x 16 x 256B)
  const size_t HB = (size_t)Bsz * Hsz * 4;         // 256 KB per packed h buffer
  unsigned int* flags = (unsigned int*)ws;
  unsigned int* hb0 = (unsigned int*)(ws + FLAGS_BYTES);
  unsigned int* hb1 = (unsigned int*)(ws + FLAGS_BYTES + HB);

  hipMemsetAsync(d_ws, 0, FLAGS_BYTES + 2 * HB, stream);

  hipLaunchKernelGGL(lstm_persistent, dim3(NBLK), dim3(NTHREADS), 0, stream,
                     x, wih, whh, bih, bhh, out, hb0, hb1, flags);
}

// Round 5
// 5080.037 us; speedup vs baseline: 2.6027x; 1.1813x over previous
//
#include <hip/hip_runtime.h>
#include <stdint.h>

// LSTM final-h. B=128, T=1024, I=256, H=512. Inputs fp32, output fp32.
// R12: conflict-free LDS + all-lane gates. R11 (6.0ms) introduced
// SQ_LDS_BANK_CONFLICT = 2.01e8 (was 0 in R8-R10): its [row][chunk^swz]
// plane layout put ~8 lanes per bank-quad on every ds_read_b128 AND the
// stage ds_write_b128s, ~1.5k conflict-cycles/step/CU on the lock-step
// critical path. Gate phase also ran on 16/64 lanes (20 transcendentals
// each). Now:
//  - planes stored in MFMA-FRAGMENT order: frag f = ks*64 + kq*16 + row.
//    MFMA reads are plane[ks*64+lane] (lane-contiguous 16B: the exact
//    pattern that measured 0 conflicts in R8-R10).
//  - stage map: lane tid loads ONE row's 64B k-slice (cidx = tid>>4;
//    global stays 64B/lane contiguous -> no LLC amplification) and
//    ds_writes fragments f1 = (cidx>>1)*64 + (cidx&1)*32 + row, f1+16:
//    per-wave contiguous 16-lane runs -> conflict-free writes.
//  - gates spread over ALL 64 lanes: lane owns (row kq*4+qg, unit ug).
//    Inputs redistributed with 3 shfl_xor of pre-selected v[qg^m]
//    (bit-identical values). Transcendentals/wave /4; 1 packed dword
//    store per lane; release ack waits 1 store.
//  - counted vmcnt(4) overlaps x-plane LDS write with h LLC load latency
//    (sched_barrier(0) after each inline-asm wait, rule #18).
// Sync protocol unchanged from R11 (zero cache-maintenance ops; WT
// sc0 sc1 h stores; LLC-direct stage loads; per-wave flags + wave0 poll).
// Numerics bit-identical to R11 (absmax 1.95e-3 there).

#define Bsz 128
#define Tsz 1024
#define Isz 256
#define Hsz 512
#define NBLK 128      // 8 domains x 16 blocks
#define NTHREADS 512  // 8 waves

typedef __attribute__((ext_vector_type(8))) short short8;
typedef __attribute__((ext_vector_type(4))) float float4v;
typedef __attribute__((ext_vector_type(4))) unsigned int uint4v;
typedef __attribute__((ext_vector_type(2))) unsigned int uint2v;

__device__ __forceinline__ float b2f(unsigned short u) {
  union { float f; unsigned int i; } v; v.i = ((unsigned int)u) << 16; return v.f;
}
__device__ __forceinline__ unsigned short f2b(float f) {
  unsigned int u = __float_as_uint(f);
  return (unsigned short)((u + 0x7fffu + ((u >> 16) & 1u)) >> 16);
}
__device__ __forceinline__ float sigmf(float x) { return 1.0f / (1.0f + __expf(-x)); }
__device__ __forceinline__ float tanhf_fast(float x) {
  float e = __expf(-2.0f * fabsf(x));
  float t = (1.0f - e) / (1.0f + e);
  return copysignf(t, x);
}
__device__ __forceinline__ short8 cvt8r(float4v u, float4v v) {
  short8 r;
  r[0] = (short)f2b(u[0]); r[1] = (short)f2b(u[1]);
  r[2] = (short)f2b(u[2]); r[3] = (short)f2b(u[3]);
  r[4] = (short)f2b(v[0]); r[5] = (short)f2b(v[1]);
  r[6] = (short)f2b(v[2]); r[7] = (short)f2b(v[3]);
  return r;
}

#define MFMA(A, B, C) __builtin_amdgcn_mfma_f32_16x16x32_bf16((A), (B), (C), 0, 0, 0)

// LLC-direct 16B load (coherent h path; bypass L1/L2).
#define LLD(dst, base, OFFB)                                              \
  asm volatile("global_load_dwordx4 %0, %1, off offset:" OFFB " sc0 sc1"  \
               : "=v"(dst) : "v"(base))
// Cached 16B load, pinned at issue point (x prefetch).
#define XLD(dst, base, OFFB)                                              \
  asm volatile("global_load_dwordx4 %0, %1, off offset:" OFFB             \
               : "=v"(dst) : "v"(base))
#define VMW(N)                                                            \
  do { asm volatile("s_waitcnt vmcnt(" #N ")" ::: "memory");              \
       __builtin_amdgcn_sched_barrier(0); } while (0)

__global__ __launch_bounds__(NTHREADS, 2) void lstm_persistent(
    const float* __restrict__ x,
    const float* __restrict__ wih,
    const float* __restrict__ whh,
    const float* __restrict__ bih,
    const float* __restrict__ bhh,
    float* __restrict__ out,
    unsigned int* __restrict__ hb0,     // h packed (hi | lo<<16), parity 0: [128][512] dwords
    unsigned int* __restrict__ hb1,     // parity 1
    unsigned int* __restrict__ flags)   // 8 domains x (16 blocks x 256B chunk: 8 wave-dwords)
{
  __shared__ short8 hhi_pl[1024];      // 16 KB: h hi fragments, f = ks*64+kq*16+row
  __shared__ short8 hlo_pl[1024];      // 16 KB: h lo fragments
  __shared__ short8 x_pl[2][512];      // 16 KB: x fragments, double-buffered

  const int tid  = threadIdx.x;
  const int wid  = tid >> 6;
  const int lane = tid & 63;
  const int l15  = lane & 15;
  const int kq   = lane >> 4;
  const int qg   = l15 >> 2;   // gate index 0..3 (i,f,g,o)
  const int ug   = l15 & 3;    // unit-within-4
  const int blk  = blockIdx.x;
  const int dom  = blk >> 4;   // 8 domains (16 batch rows each)
  const int bi   = blk & 15;   // block-in-domain: units bi*32 .. bi*32+31
  const int col  = qg * Hsz + bi * 32 + wid * 4 + ug;  // gate column
  const int rowbase = dom * 16;

  // ---- W into registers as B-fragments (one-time prologue) ----
  short8 wx[8], whhhi[16], whhlo[16];
  {
    const float* p = wih + (size_t)col * Isz + kq * 8;
#pragma unroll
    for (int ks = 0; ks < 8; ++ks) {
      float4v u0 = *(const float4v*)(p + ks * 32);
      float4v u1 = *(const float4v*)(p + ks * 32 + 4);
      wx[ks] = cvt8r(u0, u1);
    }
  }
  {
    const float* p = whh + (size_t)col * Hsz + kq * 8;
#pragma unroll
    for (int ks = 0; ks < 16; ++ks) {
      float4v u0 = *(const float4v*)(p + ks * 32);
      float4v u1 = *(const float4v*)(p + ks * 32 + 4);
      short8 hi = cvt8r(u0, u1);
      short8 lo;
#pragma unroll
      for (int e = 0; e < 4; ++e) {
        lo[e]     = (short)f2b(u0[e] - b2f((unsigned short)hi[e]));
        lo[e + 4] = (short)f2b(u1[e] - b2f((unsigned short)hi[e + 4]));
      }
      whhhi[ks] = hi; whhlo[ks] = lo;
    }
  }
  const float biasC = bih[col] + bhh[col];

  // flags: dom*1024 + bi*64 + wid (dwords); 256B per block chunk
  unsigned int* myf = flags + dom * 1024 + bi * 64 + wid;
  const unsigned int* pollp = flags + dom * 1024 + (lane >> 2) * 64 + (lane & 3) * 2;

  // ---- staging maps (fragment-ordered, conflict-free both sides) ----
  const int srow = tid & 15;            // local row this thread stages
  const int grow = rowbase + srow;      // global row
  const int cidx = tid >> 4;            // 0..31: 16-unit chunk index
  const int f1   = (cidx >> 1) * 64 + (cidx & 1) * 32 + srow;  // fragment 1; f2 = f1+16
  const float* xsrc0 = x + (size_t)grow * (Tsz * Isz) + cidx * 8;

  // ---- prologue: stage x(0) ----
  {
    float4v u0, u1;
    XLD(u0, xsrc0, "0"); XLD(u1, xsrc0, "16");
    VMW(0);
    x_pl[0][tid] = cvt8r(u0, u1);
  }
  __syncthreads();

  float cstv = 0.f;                              // cell state: row kq*4+qg, unit ug
  const int growo = rowbase + kq * 4 + qg;       // output row this lane owns
  const int hunit = bi * 32 + wid * 4 + ug;      // output unit this lane owns

  for (int t = 0; t < Tsz; ++t) {
    const int par = t & 1;

    // ---- issue x(t+1) prefetch (retires during poll/stage) ----
    float4v xu0, xu1;
    const int tn = (t + 1 < Tsz) ? t + 1 : t;
    {
      const float* xp = xsrc0 + (size_t)tn * Isz;
      XLD(xu0, xp, "0"); XLD(xu1, xp, "16");
    }

    // ---- x-part MFMAs (A from fragment-ordered LDS: lane-contiguous) ----
    float4v accm = {0.f, 0.f, 0.f, 0.f};
    float4v accc = {0.f, 0.f, 0.f, 0.f};
#pragma unroll
    for (int ks = 0; ks < 8; ++ks) {
      short8 xa = x_pl[par][ks * 64 + lane];
      accm = MFMA(xa, wx[ks], accm);
    }

    // ---- wave0 polls all 128 wave-flags of this domain ----
    if (t > 0 && wid == 0) {
      int guard = 0;
      for (;;) {
        uint2v fv;
        asm volatile("global_load_dwordx2 %0, %1, off sc0 sc1\n\t"
                     "s_waitcnt vmcnt(0)"
                     : "=v"(fv) : "v"(pollp) : "memory");
        unsigned m = fv[0] < fv[1] ? fv[0] : fv[1];
        if (__all(m >= (unsigned)t)) break;
        __builtin_amdgcn_s_sleep(1);
        if (++guard > (1 << 26)) break;  // fail loud, not hang
      }
    }
    __syncthreads();  // barrier1: h(t) globally visible; LDS planes reusable

    // ---- issue h(t) stage loads: one row 64B k-slice per thread ----
    const unsigned int* hsrc =
        ((par) ? hb1 : hb0) + (size_t)grow * Hsz + cidx * 16;
    uint4v d0, d1, d2, d3;
    LLD(d0, hsrc, "0");  LLD(d1, hsrc, "16");
    LLD(d2, hsrc, "32"); LLD(d3, hsrc, "48");

    // x loads (older in FIFO) done once <=4 outstanding: write x plane
    VMW(4);
    if (t + 1 < Tsz)
      x_pl[par ^ 1][tid] = cvt8r(xu0, xu1);

    // h loads done: unpack and write fragments (lane-contiguous runs)
    VMW(0);
    {
      short8 h0, h1, l0, l1;
#pragma unroll
      for (int e = 0; e < 4; ++e) {
        h0[e]     = (short)(d0[e] & 0xffffu); l0[e]     = (short)(d0[e] >> 16);
        h0[e + 4] = (short)(d1[e] & 0xffffu); l0[e + 4] = (short)(d1[e] >> 16);
        h1[e]     = (short)(d2[e] & 0xffffu); l1[e]     = (short)(d2[e] >> 16);
        h1[e + 4] = (short)(d3[e] & 0xffffu); l1[e + 4] = (short)(d3[e] >> 16);
      }
      hhi_pl[f1]      = h0;  hlo_pl[f1]      = l0;
      hhi_pl[f1 + 16] = h1;  hlo_pl[f1 + 16] = l1;
    }
    __syncthreads();  // barrier2: planes ready

    // ---- h-part MFMAs (W in regs, A fragment-ordered: 0-conflict reads) ----
#pragma unroll
    for (int ks = 0; ks < 16; ++ks) {
      short8 ha = hhi_pl[ks * 64 + lane];
      short8 la = hlo_pl[ks * 64 + lane];
      accm = MFMA(ha, whhhi[ks], accm);
      accc = MFMA(ha, whhlo[ks], accc);
      accc = MFMA(la, whhhi[ks], accc);
    }

    // ---- gates on ALL lanes: lane owns (row kq*4+qg, unit ug) ----
    float v0 = accm[0] + accc[0] + biasC;
    float v1 = accm[1] + accc[1] + biasC;
    float v2 = accm[2] + accc[2] + biasC;
    float v3 = accm[3] + accc[3] + biasC;
    // send v[qg^m] on exchange xor(4m); receive partner's v[qg] = gate qg^m, row qg
    int k1 = qg ^ 1, k2 = qg ^ 2, k3 = qg ^ 3;
    float s0 = (qg == 0) ? v0 : (qg == 1) ? v1 : (qg == 2) ? v2 : v3;
    float s1 = (k1 == 0) ? v0 : (k1 == 1) ? v1 : (k1 == 2) ? v2 : v3;
    float s2 = (k2 == 0) ? v0 : (k2 == 1) ? v1 : (k2 == 2) ? v2 : v3;
    float s3 = (k3 == 0) ? v0 : (k3 == 1) ? v1 : (k3 == 2) ? v2 : v3;
    float r4  = __shfl_xor(s1, 4, 64);   // gate qg^1, row qg
    float r8  = __shfl_xor(s2, 8, 64);   // gate qg^2, row qg
    float r12 = __shfl_xor(s3, 12, 64);  // gate qg^3, row qg
    float gi = (qg == 0) ? s0 : (qg == 1) ? r4 : (qg == 2) ? r8 : r12;
    float gf = (qg == 1) ? s0 : (qg == 0) ? r4 : (qg == 3) ? r8 : r12;
    float gG = (qg == 2) ? s0 : (qg == 3) ? r4 : (qg == 0) ? r8 : r12;
    float go = (qg == 3) ? s0 : (qg == 2) ? r4 : (qg == 1) ? r8 : r12;

    float ig = sigmf(gi);
    float fg = sigmf(gf);
    float gg = tanhf_fast(gG);
    float og = sigmf(go);
    float c  = fg * cstv + ig * gg;
    cstv = c;
    float hv = og * tanhf_fast(c);

    if (t == Tsz - 1) {
      out[(size_t)growo * Hsz + hunit] = hv;     // fp32 output
    } else {
      unsigned short hi16 = f2b(hv);
      unsigned short lo16 = f2b(hv - b2f(hi16));
      unsigned int pk = (unsigned int)hi16 | ((unsigned int)lo16 << 16);
      unsigned int* pp = ((par) ? hb0 : hb1) + (size_t)growo * Hsz + hunit;
      asm volatile("global_store_dword %0, %1, off sc0 sc1"
                   :: "v"(pp), "v"(pk) : "memory");
      // per-wave release: drain own WT store (acked at LLC), then flag.
      asm volatile("s_waitcnt vmcnt(0)" ::: "memory");
      if (lane == 0) {
        unsigned int fv = (unsigned)(t + 1);
        asm volatile("global_store_dword %0, %1, off sc0 sc1"
                     :: "v"(myf), "v"(fv) : "memory");
      }
    }
  }
}

extern "C" void kernel_launch(void* const* d_in, const int* in_sizes, int n_in,
                              void* d_out, int out_size, void* d_ws, size_t ws_size,
                              hipStream_t stream) {
  if (n_in < 5) return;
  long long s0 = in_sizes[0], s1 = in_sizes[1], s2 = in_sizes[2],
            s3 = in_sizes[3], s4 = in_sizes[4];
  if (!(s1 > 0 && s3 > 0 && s0 == 64 * s1 && s2 == 2 * s1 &&
        s1 == 256 * s3 && s3 == s4)) return;

  const float* x   = (const float*)d_in[0];
  const float* wih = (const float*)d_in[1];
  const float* whh = (const float*)d_in[2];
  const float* bih = (const float*)d_in[3];
  const float* bhh = (const float*)d_in[4];
  float* out = (float*)d_out;

  char* ws = (char*)d_ws;
  const size_t FLAGS_BYTES = 8 * 4096;             // 32 KB (8 domains x 16 x 256B)
  const size_t HB = (size_t)Bsz * Hsz * 4;         // 256 KB per packed h buffer
  unsigned int* flags = (unsigned int*)ws;
  unsigned int* hb0 = (unsigned int*)(ws + FLAGS_BYTES);
  unsigned int* hb1 = (unsigned int*)(ws + FLAGS_BYTES + HB);

  hipMemsetAsync(d_ws, 0, FLAGS_BYTES + 2 * HB, stream);

  hipLaunchKernelGGL(lstm_persistent, dim3(NBLK), dim3(NTHREADS), 0, stream,
                     x, wih, whh, bih, bhh, out, hb0, hb1, flags);
}